// Round 3
// baseline (276.619 us; speedup 1.0000x reference)
//
#include <hip/hip_runtime.h>
#include <math.h>

#define NUM_E   1024
#define EDIM    64
#define N_PTS   131072          // 32*64*64
#define ZQ_ELEM 8388608         // 32*64*64*64
#define AGRID   2048

// ---------------------------------------------------------------- prep: cbT + ee
// cbT[k][j] = cb[j][k]  (64 x 1024), ee[j] = sum_k cb[j][k]^2 (same fmaf order as before)
__global__ __launch_bounds__(256) void vq_prep(const float* __restrict__ cb,
                                               float* __restrict__ cbT,
                                               float* __restrict__ ee)
{
    __shared__ float tile[64][65];
    const int t  = threadIdx.x;
    const int j0 = blockIdx.x * 64;          // grid = 16
    {
        int jl = t >> 2, kq = (t & 3) * 16;
        const float4* src = (const float4*)(cb + (size_t)(j0 + jl) * 64 + kq);
#pragma unroll
        for (int i = 0; i < 4; ++i) {
            float4 v = src[i];
            tile[jl][kq + 4 * i + 0] = v.x;
            tile[jl][kq + 4 * i + 1] = v.y;
            tile[jl][kq + 4 * i + 2] = v.z;
            tile[jl][kq + 4 * i + 3] = v.w;
        }
    }
    __syncthreads();
    if (t < 64) {
        float a = 0.f;
#pragma unroll
        for (int k = 0; k < 64; ++k) a = fmaf(tile[t][k], tile[t][k], a);
        ee[j0 + t] = a;
    }
    {
        int k = t >> 2, j4 = (t & 3) * 16;
        float4* dst = (float4*)(cbT + (size_t)k * 1024 + j0 + j4);
#pragma unroll
        for (int s = 0; s < 4; ++s)
            dst[s] = make_float4(tile[j4 + 4 * s + 0][k], tile[j4 + 4 * s + 1][k],
                                 tile[j4 + 4 * s + 2][k], tile[j4 + 4 * s + 3][k]);
    }
}

// ---------------------------------------------------------------- argmin + quant (fused)
// One WG = 64 points (one (b,h) row, w=0..63), 256 threads.
// Thread tile: 4 points x 8 codes; codes chunked 128 at a time, reg-prefetched.
__global__ __launch_bounds__(256) void vq_argmin(
    const float* __restrict__ z, const float* __restrict__ cb,
    const float* __restrict__ cbT, const float* __restrict__ ee,
    float* __restrict__ idx_f, int* __restrict__ counts,
    float* __restrict__ zq, double* __restrict__ partials)
{
    __shared__ float  zt[64 * 64];     // [c][w] 16 KB
    __shared__ float  et[64 * 128];    // [k][j] 32 KB (reused: reduce, then qt)
    __shared__ float  eet[128];
    __shared__ float  zzs[64];
    __shared__ int    ibuf[64];
    __shared__ double wsum[4];

    const int tid = threadIdx.x;
    const int g   = blockIdx.x;                       // 2048 blocks: (b, h)
    const size_t zoff = ((size_t)(g >> 6) << 18) + (size_t)((g & 63) << 6);
    const float* zb = z + zoff;

    // ---- stage zt[c][w] (global is [B][C][H][W]: already k-major, float4 both sides)
    {
        int w4 = tid & 15, c0 = tid >> 4;
#pragma unroll
        for (int i = 0; i < 4; ++i) {
            int c = c0 + 16 * i;
            float4 v = *(const float4*)(zb + ((size_t)c << 12) + w4 * 4);
            *(float4*)&zt[c * 64 + w4 * 4] = v;
        }
    }
    // ---- prefetch code chunk 0 into registers (T14)
    const float4* cbT4 = (const float4*)cbT;
    const int srow = tid >> 5, scol = tid & 31;       // 8 rows/pass x 32 float4
    float4 r[8];
    float  ree = 0.f;
#pragma unroll
    for (int i = 0; i < 8; ++i) r[i] = cbT4[(size_t)(srow + 8 * i) * 256 + scol];
    if (tid < 128) ree = ee[tid];

    __syncthreads();
    if (tid < 64) {                                   // zz: same 64-chain fmaf order
        float a = 0.f;
#pragma unroll
        for (int k = 0; k < 64; ++k) { float v = zt[k * 64 + tid]; a = fmaf(v, v, a); }
        zzs[tid] = a;
    }
    __syncthreads();

    const int tx = tid & 15, ty = tid >> 4;
    float zzp[4];
#pragma unroll
    for (int p = 0; p < 4; ++p) zzp[p] = zzs[ty * 4 + p];

    float best[4]; int bidx[4];
#pragma unroll
    for (int p = 0; p < 4; ++p) { best[p] = 3.4e38f; bidx[p] = 0; }

    float4* et4 = (float4*)et;

    for (int ch = 0; ch < 8; ++ch) {
        // write staged regs -> LDS (et free here: post-compute barrier of prev iter)
#pragma unroll
        for (int i = 0; i < 8; ++i) et4[(srow + 8 * i) * 32 + scol] = r[i];
        if (tid < 128) eet[tid] = ree;
        __syncthreads();
        if (ch < 7) {                                  // prefetch next chunk
#pragma unroll
            for (int i = 0; i < 8; ++i)
                r[i] = cbT4[(size_t)(srow + 8 * i) * 256 + (ch + 1) * 32 + scol];
            if (tid < 128) ree = ee[(ch + 1) * 128 + tid];
        }

        float eev[8];
#pragma unroll
        for (int i = 0; i < 4; ++i) { eev[i] = eet[tx * 4 + i]; eev[4 + i] = eet[64 + tx * 4 + i]; }

        float acc[4][8];
#pragma unroll
        for (int p = 0; p < 4; ++p)
#pragma unroll
            for (int c = 0; c < 8; ++c) acc[p][c] = 0.f;

#pragma unroll 4
        for (int k = 0; k < 64; ++k) {
            float4 za = *(const float4*)&zt[k * 64 + ty * 4];
            float4 e0 = *(const float4*)&et[k * 128 + tx * 4];
            float4 e1 = *(const float4*)&et[k * 128 + 64 + tx * 4];
            float zav[4] = { za.x, za.y, za.z, za.w };
            float ev[8]  = { e0.x, e0.y, e0.z, e0.w, e1.x, e1.y, e1.z, e1.w };
#pragma unroll
            for (int p = 0; p < 4; ++p)
#pragma unroll
                for (int c = 0; c < 8; ++c)
                    acc[p][c] = fmaf(zav[p], ev[c], acc[p][c]);
        }

        // d = (zz+ee) - 2*dot, exact fp32 mimicry; ascending j scan, strict <
#pragma unroll
        for (int p = 0; p < 4; ++p) {
#pragma unroll
            for (int c = 0; c < 8; ++c) {
                int j = ch * 128 + ((c < 4) ? (tx * 4 + c) : (64 + tx * 4 + (c - 4)));
                float t1 = zzp[p] + eev[c];
                float d  = fmaf(-2.f, acc[p][c], t1);
                if (d < best[p]) { best[p] = d; bidx[p] = j; }
            }
        }
        __syncthreads();                               // compute done; et writable
    }

    // ---- cross-thread argmin reduction (reuse et)
    float* rv = et;                        // [64][17]
    int*   ri = (int*)(et + 64 * 17);      // [64][17]
#pragma unroll
    for (int p = 0; p < 4; ++p) {
        rv[(ty * 4 + p) * 17 + tx] = best[p];
        ri[(ty * 4 + p) * 17 + tx] = bidx[p];
    }
    __syncthreads();
    if (tid < 64) {
        float bv = rv[tid * 17]; int bi = ri[tid * 17];
#pragma unroll
        for (int t = 1; t < 16; ++t) {
            float v = rv[tid * 17 + t]; int i2 = ri[tid * 17 + t];
            if (v < bv || (v == bv && i2 < bi)) { bv = v; bi = i2; }
        }
        ibuf[tid] = bi;
        idx_f[g * 64 + tid] = (float)bi;
        atomicAdd(&counts[bi], 1);
    }
    __syncthreads();

    // ---- fused quantize: gather chosen code rows into qt[c][w] (reuse et)
    float* qt = et;                        // [64][65] strided
    {
        int p = tid >> 2, kq = (tid & 3) * 16;
        int bi = ibuf[p];
        const float4* crow = (const float4*)(cb + ((size_t)bi << 6) + kq);
#pragma unroll
        for (int s = 0; s < 4; ++s) {
            float4 v = crow[s];
            qt[(kq + 4 * s + 0) * 65 + p] = v.x;
            qt[(kq + 4 * s + 1) * 65 + p] = v.y;
            qt[(kq + 4 * s + 2) * 65 + p] = v.z;
            qt[(kq + 4 * s + 3) * 65 + p] = v.w;
        }
    }
    __syncthreads();
    // ---- z_q_st = fl(z + fl(q - z)), write [B][C][H][W]; loss partial
    {
        int p = tid & 63, cq = tid >> 6;
        float* zqb = zq + zoff + p;
        double ls = 0.0;
#pragma unroll
        for (int i = 0; i < 16; ++i) {
            int c = cq * 16 + i;
            float zv = zt[c * 64 + p];
            float qv = qt[c * 65 + p];
            float td = qv - zv;
            zqb[(size_t)c << 12] = zv + td;
            ls += (double)td * td;
        }
#pragma unroll
        for (int off = 32; off > 0; off >>= 1) ls += __shfl_down(ls, off);
        if ((tid & 63) == 0) wsum[tid >> 6] = ls;
    }
    __syncthreads();
    if (tid == 0) partials[g] = wsum[0] + wsum[1] + wsum[2] + wsum[3];
}

// ---------------------------------------------------------------- scalars
__global__ __launch_bounds__(256) void vq_final(
    const int* __restrict__ counts, const double* __restrict__ partials,
    float* __restrict__ scalars)
{
    __shared__ double sh[256];
    __shared__ double sl[256];
    int t = threadIdx.x;
    double s = 0.0;
    for (int j = t; j < NUM_E; j += 256) {
        float em   = (float)counts[j] * (1.0f / 131072.0f);
        float term = em * logf(em + 1e-10f);
        s += (double)term;
    }
    double l = 0.0;
#pragma unroll
    for (int j = 0; j < AGRID / 256; ++j) l += partials[j * 256 + t];
    sh[t] = s;
    sl[t] = l;
    __syncthreads();
    for (int off = 128; off > 0; off >>= 1) {
        if (t < off) { sh[t] += sh[t + off]; sl[t] += sl[t + off]; }
        __syncthreads();
    }
    if (t == 0) {
        float m = (float)(sl[0] / 8388608.0);
        scalars[0] = m + 0.5f * m;           // mean1 + BETA*mean2
        scalars[1] = expf(-(float)sh[0]);    // perplexity
    }
}

// ---------------------------------------------------------------- launch
extern "C" void kernel_launch(void* const* d_in, const int* in_sizes, int n_in,
                              void* d_out, int out_size, void* d_ws, size_t ws_size,
                              hipStream_t stream)
{
    const float* z  = (const float*)d_in[0];
    const float* cb = (const float*)d_in[1];
    float* out     = (float*)d_out;
    float* zq      = out;                    // [32,64,64,64]
    float* scalars = out + ZQ_ELEM;          // loss, perplexity
    float* idx_f   = out + ZQ_ELEM + 2;      // [32,64,64] as float

    int*    counts   = (int*)d_ws;                            // 4 KB
    double* partials = (double*)((char*)d_ws + 4096);         // 16 KB
    float*  ee       = (float*)((char*)d_ws + 4096 + 16384);  // 4 KB
    float*  cbT      = (float*)((char*)d_ws + 4096 + 16384 + 4096);  // 256 KB

    hipMemsetAsync(d_ws, 0, 4096, stream);                    // zero counts
    vq_prep  <<<16,    256, 0, stream>>>(cb, cbT, ee);
    vq_argmin<<<AGRID, 256, 0, stream>>>(z, cb, cbT, ee, idx_f, counts, zq, partials);
    vq_final <<<1,     256, 0, stream>>>(counts, partials, scalars);
}

// Round 4
// 251.016 us; speedup vs baseline: 1.1020x; 1.1020x over previous
//
#include <hip/hip_runtime.h>
#include <math.h>

#define NUM_E   1024
#define EDIM    64
#define ZQ_ELEM 8388608         // 32*64*64*64
#define AGRID   1024

// ---------------------------------------------------------------- prep: cbT + ee
// cbT[k][j] = cb[j][k]  (64 x 1024), ee[j] = sum_k cb[j][k]^2 (fixed fmaf chain)
__global__ __launch_bounds__(256) void vq_prep(const float* __restrict__ cb,
                                               float* __restrict__ cbT,
                                               float* __restrict__ ee)
{
    __shared__ float tile[64][65];
    const int t  = threadIdx.x;
    const int j0 = blockIdx.x * 64;          // grid = 16
    {
        int jl = t >> 2, kq = (t & 3) * 16;
        const float4* src = (const float4*)(cb + (size_t)(j0 + jl) * 64 + kq);
#pragma unroll
        for (int i = 0; i < 4; ++i) {
            float4 v = src[i];
            tile[jl][kq + 4 * i + 0] = v.x;
            tile[jl][kq + 4 * i + 1] = v.y;
            tile[jl][kq + 4 * i + 2] = v.z;
            tile[jl][kq + 4 * i + 3] = v.w;
        }
    }
    __syncthreads();
    if (t < 64) {
        float a = 0.f;
#pragma unroll
        for (int k = 0; k < 64; ++k) a = fmaf(tile[t][k], tile[t][k], a);
        ee[j0 + t] = a;
    }
    {
        int k = t >> 2, j4 = (t & 3) * 16;
        float4* dst = (float4*)(cbT + (size_t)k * 1024 + j0 + j4);
#pragma unroll
        for (int s = 0; s < 4; ++s)
            dst[s] = make_float4(tile[j4 + 4 * s + 0][k], tile[j4 + 4 * s + 1][k],
                                 tile[j4 + 4 * s + 2][k], tile[j4 + 4 * s + 3][k]);
    }
}

// ---------------------------------------------------------------- argmin + quant (fused)
// One WG = 128 points (two adjacent h-rows), 256 threads.
// Thread tile: 8 points x 8 codes; codes chunked 128 at a time, reg-prefetched.
__global__ __launch_bounds__(256) void vq_argmin(
    const float* __restrict__ z, const float* __restrict__ cb,
    const float* __restrict__ cbT, const float* __restrict__ ee,
    float* __restrict__ idx_f, int* __restrict__ counts,
    float* __restrict__ zq, double* __restrict__ partials)
{
    __shared__ float  zt[128 * 64];    // [k][p] 32 KB
    __shared__ float  et[64 * 128];    // [k][j] 32 KB (reused: reduce, then qt)
    __shared__ float  eet[128];
    __shared__ float  zzs[128];
    __shared__ int    ibuf[128];
    __shared__ double wsum[4];

    const int tid = threadIdx.x;
    const int g   = blockIdx.x;                       // 1024 blocks: (b, hpair)
    const size_t zoff = ((size_t)(g >> 5) << 18) + (size_t)((g & 31) << 7);
    const float4* zb4 = (const float4*)(z + zoff);
    float4* zt4 = (float4*)zt;
    float4* et4 = (float4*)et;

    // ---- stage zt[k][p]: per c, 128 contiguous floats (two h-rows)
    {
        int w8 = tid & 31, c0 = tid >> 5;
#pragma unroll
        for (int i = 0; i < 8; ++i) {
            int c = c0 + 8 * i;
            zt4[c * 32 + w8] = zb4[(size_t)c * 1024 + w8];
        }
    }
    // ---- prefetch code chunk 0 into registers (T14)
    const float4* cbT4 = (const float4*)cbT;
    const int srow = tid >> 5, scol = tid & 31;       // 8 k-rows/pass x 32 float4
    float4 r[8];
    float  ree = 0.f;
#pragma unroll
    for (int i = 0; i < 8; ++i) r[i] = cbT4[(size_t)(srow + 8 * i) * 256 + scol];
    if (tid < 128) ree = ee[tid];

    __syncthreads();
    if (tid < 128) {                                  // zz: same 64-chain fmaf order
        float a = 0.f;
#pragma unroll
        for (int k = 0; k < 64; ++k) { float v = zt[k * 128 + tid]; a = fmaf(v, v, a); }
        zzs[tid] = a;
    }
    __syncthreads();

    const int tx = tid & 15, ty = tid >> 4;           // ty 0..15: 8 points each
    float zzp[8];
#pragma unroll
    for (int p = 0; p < 8; ++p) zzp[p] = zzs[ty * 8 + p];

    float best[8]; int bidx[8];
#pragma unroll
    for (int p = 0; p < 8; ++p) { best[p] = 3.4e38f; bidx[p] = 0; }

    for (int ch = 0; ch < 8; ++ch) {
        // write staged regs -> LDS (et free: post-compute barrier of prev iter)
#pragma unroll
        for (int i = 0; i < 8; ++i) et4[(srow + 8 * i) * 32 + scol] = r[i];
        if (tid < 128) eet[tid] = ree;
        __syncthreads();
        if (ch < 7) {                                  // prefetch next chunk
#pragma unroll
            for (int i = 0; i < 8; ++i)
                r[i] = cbT4[(size_t)(srow + 8 * i) * 256 + (ch + 1) * 32 + scol];
            if (tid < 128) ree = ee[(ch + 1) * 128 + tid];
        }

        float eev[8];
#pragma unroll
        for (int i = 0; i < 4; ++i) { eev[i] = eet[tx * 4 + i]; eev[4 + i] = eet[64 + tx * 4 + i]; }

        float acc[8][8];
#pragma unroll
        for (int p = 0; p < 8; ++p)
#pragma unroll
            for (int c = 0; c < 8; ++c) acc[p][c] = 0.f;

#pragma unroll 2
        for (int k = 0; k < 64; ++k) {
            float4 a0 = zt4[k * 32 + ty * 2];
            float4 a1 = zt4[k * 32 + ty * 2 + 1];
            float4 e0 = et4[k * 32 + tx];
            float4 e1 = et4[k * 32 + 16 + tx];
            float zav[8] = { a0.x, a0.y, a0.z, a0.w, a1.x, a1.y, a1.z, a1.w };
            float ev[8]  = { e0.x, e0.y, e0.z, e0.w, e1.x, e1.y, e1.z, e1.w };
#pragma unroll
            for (int p = 0; p < 8; ++p)
#pragma unroll
                for (int c = 0; c < 8; ++c)
                    acc[p][c] = fmaf(zav[p], ev[c], acc[p][c]);
        }

        // d = (zz+ee) - 2*dot, exact fp32 mimicry; ascending j scan, strict <
#pragma unroll
        for (int p = 0; p < 8; ++p) {
#pragma unroll
            for (int c = 0; c < 8; ++c) {
                int j = ch * 128 + ((c < 4) ? (tx * 4 + c) : (64 + tx * 4 + (c - 4)));
                float t1 = zzp[p] + eev[c];
                float d  = fmaf(-2.f, acc[p][c], t1);
                if (d < best[p]) { best[p] = d; bidx[p] = j; }
            }
        }
        __syncthreads();                               // compute done; et writable
    }

    // ---- cross-thread argmin reduction (reuse et): rv/ri [128][17]
    float* rv = et;
    int*   ri = (int*)(et + 128 * 17);
#pragma unroll
    for (int p = 0; p < 8; ++p) {
        rv[(ty * 8 + p) * 17 + tx] = best[p];
        ri[(ty * 8 + p) * 17 + tx] = bidx[p];
    }
    __syncthreads();
    if (tid < 128) {
        float bv = rv[tid * 17]; int bi = ri[tid * 17];
#pragma unroll
        for (int t = 1; t < 16; ++t) {
            float v = rv[tid * 17 + t]; int i2 = ri[tid * 17 + t];
            if (v < bv || (v == bv && i2 < bi)) { bv = v; bi = i2; }  // lowest-idx tie
        }
        ibuf[tid] = bi;
        idx_f[g * 128 + tid] = (float)bi;
        atomicAdd(&counts[bi], 1);
    }
    __syncthreads();

    // ---- gather chosen code rows into qt[c][p] (reuse et, 8192 floats exactly)
    float* qt = et;
    {
        int p = tid >> 1, kq = (tid & 1) * 32;        // half-row per thread
        int bi = ibuf[p];
        const float4* crow = (const float4*)(cb + ((size_t)bi << 6) + kq);
#pragma unroll
        for (int s = 0; s < 8; ++s) {
            float4 v = crow[s];
            qt[(kq + 4 * s + 0) * 128 + p] = v.x;
            qt[(kq + 4 * s + 1) * 128 + p] = v.y;
            qt[(kq + 4 * s + 2) * 128 + p] = v.z;
            qt[(kq + 4 * s + 3) * 128 + p] = v.w;
        }
    }
    __syncthreads();
    // ---- z_q_st = fl(z + fl(q - z)), float4 stores; loss partial
    {
        int w4 = tid & 31, cb8 = (tid >> 5) * 8;
        float4* zq4 = (float4*)(zq + zoff);
        double ls = 0.0;
#pragma unroll
        for (int i = 0; i < 8; ++i) {
            int c = cb8 + i;
            float4 zv = zt4[c * 32 + w4];
            float q0 = qt[c * 128 + w4 * 4 + 0];
            float q1 = qt[c * 128 + w4 * 4 + 1];
            float q2 = qt[c * 128 + w4 * 4 + 2];
            float q3 = qt[c * 128 + w4 * 4 + 3];
            float t0 = q0 - zv.x, t1 = q1 - zv.y, t2 = q2 - zv.z, t3 = q3 - zv.w;
            zq4[(size_t)c * 1024 + w4] =
                make_float4(zv.x + t0, zv.y + t1, zv.z + t2, zv.w + t3);
            ls += (double)t0 * t0 + (double)t1 * t1 + (double)t2 * t2 + (double)t3 * t3;
        }
#pragma unroll
        for (int off = 32; off > 0; off >>= 1) ls += __shfl_down(ls, off);
        if ((tid & 63) == 0) wsum[tid >> 6] = ls;
    }
    __syncthreads();
    if (tid == 0) partials[g] = wsum[0] + wsum[1] + wsum[2] + wsum[3];
}

// ---------------------------------------------------------------- scalars
__global__ __launch_bounds__(256) void vq_final(
    const int* __restrict__ counts, const double* __restrict__ partials,
    float* __restrict__ scalars)
{
    __shared__ double sh[256];
    __shared__ double sl[256];
    int t = threadIdx.x;
    double s = 0.0;
    for (int j = t; j < NUM_E; j += 256) {
        float em   = (float)counts[j] * (1.0f / 131072.0f);
        float term = em * logf(em + 1e-10f);
        s += (double)term;
    }
    double l = 0.0;
#pragma unroll
    for (int j = 0; j < AGRID / 256; ++j) l += partials[j * 256 + t];
    sh[t] = s;
    sl[t] = l;
    __syncthreads();
    for (int off = 128; off > 0; off >>= 1) {
        if (t < off) { sh[t] += sh[t + off]; sl[t] += sl[t + off]; }
        __syncthreads();
    }
    if (t == 0) {
        float m = (float)(sl[0] / 8388608.0);
        scalars[0] = m + 0.5f * m;           // mean1 + BETA*mean2
        scalars[1] = expf(-(float)sh[0]);    // perplexity
    }
}

// ---------------------------------------------------------------- launch
extern "C" void kernel_launch(void* const* d_in, const int* in_sizes, int n_in,
                              void* d_out, int out_size, void* d_ws, size_t ws_size,
                              hipStream_t stream)
{
    const float* z  = (const float*)d_in[0];
    const float* cb = (const float*)d_in[1];
    float* out     = (float*)d_out;
    float* zq      = out;                    // [32,64,64,64]
    float* scalars = out + ZQ_ELEM;          // loss, perplexity
    float* idx_f   = out + ZQ_ELEM + 2;      // [32,64,64] as float

    int*    counts   = (int*)d_ws;                            // 4 KB
    double* partials = (double*)((char*)d_ws + 4096);         // 8 KB
    float*  ee       = (float*)((char*)d_ws + 4096 + 8192);   // 4 KB
    float*  cbT      = (float*)((char*)d_ws + 4096 + 8192 + 4096);  // 256 KB

    hipMemsetAsync(d_ws, 0, 4096, stream);                    // zero counts
    vq_prep  <<<16,    256, 0, stream>>>(cb, cbT, ee);
    vq_argmin<<<AGRID, 256, 0, stream>>>(z, cb, cbT, ee, idx_f, counts, zq, partials);
    vq_final <<<1,     256, 0, stream>>>(counts, partials, scalars);
}

// Round 5
// 149.347 us; speedup vs baseline: 1.8522x; 1.6808x over previous
//
#include <hip/hip_runtime.h>
#include <math.h>

#define NUM_E   1024
#define ZQ_ELEM 8388608         // 32*64*64*64
#define AGRID   1024
#define QCAP    2048
#define WIN     2e-4f

typedef short bf16x8 __attribute__((ext_vector_type(8)));
typedef float f32x16 __attribute__((ext_vector_type(16)));

__device__ inline unsigned short rne_bf16(float v) {
    unsigned u = __float_as_uint(v);
    return (unsigned short)((u + 0x7FFFu + ((u >> 16) & 1u)) >> 16);  // RNE, finite-safe
}

// ---------------------------------------------------------------- prep: ee + bf16 hi/lo B-fragments
// B-frag layout for mfma_f32_32x32x16_bf16: lane l holds col j = nt*32+(l&31),
// k = kt*16 + (l>>5)*8 + i.  Packet index = (nt*4+kt)*64 + (l>>5)*32 + (j&31).
__global__ __launch_bounds__(256) void vq_prep(const float* __restrict__ cb,
                                               float* __restrict__ ee,
                                               unsigned short* __restrict__ ehi,
                                               unsigned short* __restrict__ elo)
{
    int j = blockIdx.x * 256 + threadIdx.x;   // grid 4 -> 1024 codes
    const float* r = cb + (size_t)j * 64;
    float v[64];
#pragma unroll
    for (int k = 0; k < 64; ++k) v[k] = r[k];
    float a = 0.f;
#pragma unroll
    for (int k = 0; k < 64; ++k) a = fmaf(v[k], v[k], a);   // same chain as r1-r4
    ee[j] = a;

    int nt = j >> 5, jc = j & 31;
#pragma unroll
    for (int kt = 0; kt < 4; ++kt)
#pragma unroll
        for (int h = 0; h < 2; ++h) {
            bf16x8 vh, vl;
#pragma unroll
            for (int i = 0; i < 8; ++i) {
                float x = v[kt * 16 + h * 8 + i];
                unsigned short hb = rne_bf16(x);
                float hf = __uint_as_float((unsigned)hb << 16);
                vh[i] = (short)hb;
                vl[i] = (short)rne_bf16(x - hf);
            }
            size_t pkt = ((size_t)(nt * 4 + kt) * 64 + h * 32 + jc) * 8;
            *(bf16x8*)(ehi + pkt) = vh;
            *(bf16x8*)(elo + pkt) = vl;
        }
}

// ---------------------------------------------------------------- argmin + quant (fused, MFMA-filtered)
// Block = 128 points (2 h-rows), 256 threads = 4 waves; wave wv owns points wv*32..wv*32+31.
__global__ __launch_bounds__(256) void vq_argmin(
    const float* __restrict__ z, const float* __restrict__ cb,
    const unsigned short* __restrict__ ehi, const unsigned short* __restrict__ elo,
    const float* __restrict__ ee,
    float* __restrict__ idx_f, int* __restrict__ counts,
    float* __restrict__ zq, double* __restrict__ partials)
{
    __shared__ float zt[64 * 128];             // 32 KB [k][p]
    __shared__ float eeL[1024];                // 4 KB
    __shared__ float zzs[128];
    __shared__ unsigned long long best[128];   // packed (d_bits<<32)|j
    __shared__ unsigned int queue[QCAP];       // 8 KB: (pl<<16)|j
    __shared__ unsigned int qcnt;
    __shared__ int ibuf[128];
    __shared__ double wsum[4];

    const int tid  = threadIdx.x;
    const int g    = blockIdx.x;               // 1024 blocks
    const int lane = tid & 63, wv = tid >> 6;
    const size_t zoff = ((size_t)(g >> 5) << 18) + (size_t)((g & 31) << 7);
    const float4* zb4 = (const float4*)(z + zoff);
    float4* zt4 = (float4*)zt;

    // ---- stage zt[k][p] (coalesced), eeL, init best/qcnt
    {
        int w8 = tid & 31, c0 = tid >> 5;
#pragma unroll
        for (int i = 0; i < 8; ++i) {
            int c = c0 + 8 * i;
            zt4[c * 32 + w8] = zb4[(size_t)c * 1024 + w8];
        }
#pragma unroll
        for (int i = 0; i < 4; ++i) eeL[i * 256 + tid] = ee[i * 256 + tid];
        if (tid < 128) best[tid] = 0xFFFFFFFFFFFFFFFFull;
        if (tid == 0) qcnt = 0;
    }
    __syncthreads();
    if (tid < 128) {                            // zz: same 64-chain fmaf order as r1-r4
        float a = 0.f;
#pragma unroll
        for (int k = 0; k < 64; ++k) { float v = zt[k * 128 + tid]; a = fmaf(v, v, a); }
        zzs[tid] = a;
    }

    // ---- build A-fragments (z hi/lo) in registers
    // A layout: lane l holds row = l&31 (point wv*32+(l&31)), k = kt*16+(l>>5)*8+i
    bf16x8 ah[4], al[4];
    {
        int pl = wv * 32 + (lane & 31), h = lane >> 5;
#pragma unroll
        for (int kt = 0; kt < 4; ++kt)
#pragma unroll
            for (int i = 0; i < 8; ++i) {
                int k = kt * 16 + h * 8 + i;
                float x = zt[k * 128 + pl];
                unsigned short hb = rne_bf16(x);
                float hf = __uint_as_float((unsigned)hb << 16);
                ah[kt][i] = (short)hb;
                al[kt][i] = (short)rne_bf16(x - hf);
            }
    }

    const bf16x8* eh8 = (const bf16x8*)ehi;
    const bf16x8* el8 = (const bf16x8*)elo;
    const int plbase = wv * 32 + 4 * (lane >> 5);

    float mreg[16];
#pragma unroll
    for (int r = 0; r < 16; ++r) mreg[r] = 3.4e38f;

    // ---- sweep 1: min_j s~  (per-wave, barrier-free)
    for (int nt = 0; nt < 32; ++nt) {
        f32x16 acc;
#pragma unroll
        for (int r = 0; r < 16; ++r) acc[r] = 0.f;
#pragma unroll
        for (int kt = 0; kt < 4; ++kt) {
            bf16x8 bh = eh8[(nt * 4 + kt) * 64 + lane];
            bf16x8 bl = el8[(nt * 4 + kt) * 64 + lane];
            acc = __builtin_amdgcn_mfma_f32_32x32x16_bf16(ah[kt], bh, acc, 0, 0, 0);
            acc = __builtin_amdgcn_mfma_f32_32x32x16_bf16(ah[kt], bl, acc, 0, 0, 0);
            acc = __builtin_amdgcn_mfma_f32_32x32x16_bf16(al[kt], bh, acc, 0, 0, 0);
        }
        float eej = eeL[nt * 32 + (lane & 31)];
#pragma unroll
        for (int r = 0; r < 16; ++r) {
            float s = fmaf(-2.f, acc[r], eej);
            mreg[r] = fminf(mreg[r], s);
        }
    }
    // butterfly min across the 32 cols (lanes sharing l>>5 hold same rows)
#pragma unroll
    for (int r = 0; r < 16; ++r)
        for (int d2 = 1; d2 <= 16; d2 <<= 1)
            mreg[r] = fminf(mreg[r], __shfl_xor(mreg[r], d2));

    // ---- sweep 2: recompute (bit-identical) and enqueue window hits
    for (int nt = 0; nt < 32; ++nt) {
        f32x16 acc;
#pragma unroll
        for (int r = 0; r < 16; ++r) acc[r] = 0.f;
#pragma unroll
        for (int kt = 0; kt < 4; ++kt) {
            bf16x8 bh = eh8[(nt * 4 + kt) * 64 + lane];
            bf16x8 bl = el8[(nt * 4 + kt) * 64 + lane];
            acc = __builtin_amdgcn_mfma_f32_32x32x16_bf16(ah[kt], bh, acc, 0, 0, 0);
            acc = __builtin_amdgcn_mfma_f32_32x32x16_bf16(ah[kt], bl, acc, 0, 0, 0);
            acc = __builtin_amdgcn_mfma_f32_32x32x16_bf16(al[kt], bh, acc, 0, 0, 0);
        }
        float eej = eeL[nt * 32 + (lane & 31)];
        unsigned jj = (unsigned)(nt * 32 + (lane & 31));
#pragma unroll
        for (int r = 0; r < 16; ++r) {
            float s = fmaf(-2.f, acc[r], eej);
            if (s <= mreg[r] + WIN) {
                unsigned slot = atomicAdd(&qcnt, 1u);
                if (slot < QCAP)
                    queue[slot] = ((unsigned)(plbase + ((r & 3) + 8 * (r >> 2))) << 16) | jj;
            }
        }
    }
    __syncthreads();

    // ---- exact refine of candidates (bit-identical to r1-r4 formula)
    {
        int nq = (int)min(qcnt, (unsigned)QCAP);
        for (int e = tid; e < nq; e += 256) {
            unsigned u = queue[e];
            int pl = u >> 16, j = u & 0xFFFF;
            const float4* cr = (const float4*)(cb + ((size_t)j << 6));
            float a = 0.f;
#pragma unroll
            for (int q = 0; q < 16; ++q) {
                float4 c4 = cr[q];
                a = fmaf(zt[(4 * q + 0) * 128 + pl], c4.x, a);
                a = fmaf(zt[(4 * q + 1) * 128 + pl], c4.y, a);
                a = fmaf(zt[(4 * q + 2) * 128 + pl], c4.z, a);
                a = fmaf(zt[(4 * q + 3) * 128 + pl], c4.w, a);
            }
            float t1 = zzs[pl] + eeL[j];
            float d  = fmaf(-2.f, a, t1);
            unsigned long long key =
                ((unsigned long long)__float_as_uint(d) << 32) | (unsigned long long)j;
            atomicMin(&best[pl], key);            // lexicographic (d, j): lowest idx on tie
        }
    }
    __syncthreads();
    if (tid < 128) {
        int bi = (int)(best[tid] & 0xFFFFFFFFull);
        ibuf[tid] = bi;
        idx_f[(size_t)g * 128 + tid] = (float)bi;
        atomicAdd(&counts[bi], 1);
    }
    __syncthreads();

    // ---- fused tail: z_q_st = fl(z + fl(q - z)), float4 stores; loss partial
    {
        int w4 = tid & 31, c8 = (tid >> 5) * 8;
        float4* zq4 = (float4*)(zq + zoff);
        size_t b0 = (size_t)ibuf[w4 * 4 + 0] << 6;
        size_t b1 = (size_t)ibuf[w4 * 4 + 1] << 6;
        size_t b2 = (size_t)ibuf[w4 * 4 + 2] << 6;
        size_t b3 = (size_t)ibuf[w4 * 4 + 3] << 6;
        double ls = 0.0;
#pragma unroll
        for (int i = 0; i < 8; ++i) {
            int c = c8 + i;
            float4 zv = zt4[c * 32 + w4];
            float q0 = cb[b0 + c], q1 = cb[b1 + c], q2 = cb[b2 + c], q3 = cb[b3 + c];
            float t0 = q0 - zv.x, t1 = q1 - zv.y, t2 = q2 - zv.z, t3 = q3 - zv.w;
            zq4[(size_t)c * 1024 + w4] =
                make_float4(zv.x + t0, zv.y + t1, zv.z + t2, zv.w + t3);
            ls += (double)t0 * t0 + (double)t1 * t1 + (double)t2 * t2 + (double)t3 * t3;
        }
#pragma unroll
        for (int off = 32; off > 0; off >>= 1) ls += __shfl_down(ls, off);
        if ((tid & 63) == 0) wsum[tid >> 6] = ls;
    }
    __syncthreads();
    if (tid == 0) partials[g] = wsum[0] + wsum[1] + wsum[2] + wsum[3];
}

// ---------------------------------------------------------------- scalars
__global__ __launch_bounds__(256) void vq_final(
    const int* __restrict__ counts, const double* __restrict__ partials,
    float* __restrict__ scalars)
{
    __shared__ double sh[256];
    __shared__ double sl[256];
    int t = threadIdx.x;
    double s = 0.0;
    for (int j = t; j < NUM_E; j += 256) {
        float em   = (float)counts[j] * (1.0f / 131072.0f);
        float term = em * logf(em + 1e-10f);
        s += (double)term;
    }
    double l = 0.0;
#pragma unroll
    for (int j = 0; j < AGRID / 256; ++j) l += partials[j * 256 + t];
    sh[t] = s;
    sl[t] = l;
    __syncthreads();
    for (int off = 128; off > 0; off >>= 1) {
        if (t < off) { sh[t] += sh[t + off]; sl[t] += sl[t + off]; }
        __syncthreads();
    }
    if (t == 0) {
        float m = (float)(sl[0] / 8388608.0);
        scalars[0] = m + 0.5f * m;           // mean1 + BETA*mean2
        scalars[1] = expf(-(float)sh[0]);    // perplexity
    }
}

// ---------------------------------------------------------------- launch
extern "C" void kernel_launch(void* const* d_in, const int* in_sizes, int n_in,
                              void* d_out, int out_size, void* d_ws, size_t ws_size,
                              hipStream_t stream)
{
    const float* z  = (const float*)d_in[0];
    const float* cb = (const float*)d_in[1];
    float* out     = (float*)d_out;
    float* zq      = out;                    // [32,64,64,64]
    float* scalars = out + ZQ_ELEM;          // loss, perplexity
    float* idx_f   = out + ZQ_ELEM + 2;      // [32,64,64] as float

    int*            counts   = (int*)d_ws;                               // 4 KB
    double*         partials = (double*)((char*)d_ws + 4096);            // 8 KB
    float*          ee       = (float*)((char*)d_ws + 12288);            // 4 KB
    unsigned short* ehi      = (unsigned short*)((char*)d_ws + 16384);   // 128 KB
    unsigned short* elo      = (unsigned short*)((char*)d_ws + 147456);  // 128 KB

    hipMemsetAsync(d_ws, 0, 4096, stream);                    // zero counts
    vq_prep  <<<4,     256, 0, stream>>>(cb, ee, ehi, elo);
    vq_argmin<<<AGRID, 256, 0, stream>>>(z, cb, ehi, elo, ee, idx_f, counts, zq, partials);
    vq_final <<<1,     256, 0, stream>>>(counts, partials, scalars);
}

// Round 6
// 141.232 us; speedup vs baseline: 1.9586x; 1.0575x over previous
//
#include <hip/hip_runtime.h>
#include <math.h>

#define NUM_E   1024
#define ZQ_ELEM 8388608         // 32*64*64*64
#define AGRID   1024
#define QCAP    1024
#define WIN     2e-4f

typedef short bf16x8 __attribute__((ext_vector_type(8)));
typedef float f32x16 __attribute__((ext_vector_type(16)));

__device__ inline unsigned short rne_bf16(float v) {
    unsigned u = __float_as_uint(v);
    return (unsigned short)((u + 0x7FFFu + ((u >> 16) & 1u)) >> 16);  // RNE, finite-safe
}

// ---------------------------------------------------------------- prep: ee + bf16 hi/lo B-fragments
// B-frag layout for mfma_f32_32x32x16_bf16: lane l holds col j = nt*32+(l&31),
// k = kt*16 + (l>>5)*8 + i.  Packet index = (nt*4+kt)*64 + (l>>5)*32 + (j&31).
__global__ __launch_bounds__(256) void vq_prep(const float* __restrict__ cb,
                                               float* __restrict__ ee,
                                               unsigned short* __restrict__ ehi,
                                               unsigned short* __restrict__ elo)
{
    int j = blockIdx.x * 256 + threadIdx.x;   // grid 4 -> 1024 codes
    const float* r = cb + (size_t)j * 64;
    float v[64];
#pragma unroll
    for (int k = 0; k < 64; ++k) v[k] = r[k];
    float a = 0.f;
#pragma unroll
    for (int k = 0; k < 64; ++k) a = fmaf(v[k], v[k], a);   // same chain as r1-r5
    ee[j] = a;

    int nt = j >> 5, jc = j & 31;
#pragma unroll
    for (int kt = 0; kt < 4; ++kt)
#pragma unroll
        for (int h = 0; h < 2; ++h) {
            bf16x8 vh, vl;
#pragma unroll
            for (int i = 0; i < 8; ++i) {
                float x = v[kt * 16 + h * 8 + i];
                unsigned short hb = rne_bf16(x);
                float hf = __uint_as_float((unsigned)hb << 16);
                vh[i] = (short)hb;
                vl[i] = (short)rne_bf16(x - hf);
            }
            size_t pkt = ((size_t)(nt * 4 + kt) * 64 + h * 32 + jc) * 8;
            *(bf16x8*)(ehi + pkt) = vh;
            *(bf16x8*)(elo + pkt) = vl;
        }
}

// ---------------------------------------------------------------- argmin + quant (fused, MFMA-filtered)
// Block = 128 points (2 h-rows), 256 threads = 4 waves; wave wv owns points wv*32..wv*32+31.
// B packets register-double-buffered (prefetch nt+1 while computing nt).

#define LOADB(H, L, EV, ntv) do {                                   \
    int _b = ((ntv) * 4) * 64 + lane;                               \
    _Pragma("unroll")                                               \
    for (int _k = 0; _k < 4; ++_k) {                                \
        H[_k] = eh8[_b + _k * 64];                                  \
        L[_k] = el8[_b + _k * 64];                                  \
    }                                                               \
    EV = ee[(ntv) * 32 + (lane & 31)];                              \
} while (0)

#define MFMA3(H, L, ACC)                                            \
    _Pragma("unroll")                                               \
    for (int _kt = 0; _kt < 4; ++_kt) {                             \
        ACC = __builtin_amdgcn_mfma_f32_32x32x16_bf16(ah[_kt], H[_kt], ACC, 0, 0, 0); \
        ACC = __builtin_amdgcn_mfma_f32_32x32x16_bf16(ah[_kt], L[_kt], ACC, 0, 0, 0); \
        ACC = __builtin_amdgcn_mfma_f32_32x32x16_bf16(al[_kt], H[_kt], ACC, 0, 0, 0); \
    }

__global__ __launch_bounds__(256, 3) void vq_argmin(
    const float* __restrict__ z, const float* __restrict__ cb,
    const unsigned short* __restrict__ ehi, const unsigned short* __restrict__ elo,
    const float* __restrict__ ee,
    float* __restrict__ idx_f, int* __restrict__ counts,
    float* __restrict__ zq, double* __restrict__ partials)
{
    __shared__ float zt[64 * 128];             // 32 KB [k][p]
    __shared__ float zzs[128];
    __shared__ unsigned long long best[128];   // packed (d_bits<<32)|j
    __shared__ unsigned int queue[QCAP];       // 4 KB: (pl<<16)|j
    __shared__ unsigned int qcnt;
    __shared__ int ibuf[128];
    __shared__ double wsum[4];

    const int tid  = threadIdx.x;
    const int g    = blockIdx.x;               // 1024 blocks
    const int lane = tid & 63, wv = tid >> 6;
    const size_t zoff = ((size_t)(g >> 5) << 18) + (size_t)((g & 31) << 7);
    const float4* zb4 = (const float4*)(z + zoff);
    float4* zt4 = (float4*)zt;
    const bf16x8* eh8 = (const bf16x8*)ehi;
    const bf16x8* el8 = (const bf16x8*)elo;

    // ---- stage zt[k][p] (coalesced), init best/qcnt
    {
        int w8 = tid & 31, c0 = tid >> 5;
#pragma unroll
        for (int i = 0; i < 8; ++i) {
            int c = c0 + 8 * i;
            zt4[c * 32 + w8] = zb4[(size_t)c * 1024 + w8];
        }
        if (tid < 128) best[tid] = 0xFFFFFFFFFFFFFFFFull;
        if (tid == 0) qcnt = 0;
    }
    __syncthreads();
    if (tid < 128) {                            // zz: same 64-chain fmaf order as r1-r5
        float a = 0.f;
#pragma unroll
        for (int k = 0; k < 64; ++k) { float v = zt[k * 128 + tid]; a = fmaf(v, v, a); }
        zzs[tid] = a;
    }

    // ---- build A-fragments (z hi/lo) in registers
    bf16x8 ah[4], al[4];
    {
        int pl = wv * 32 + (lane & 31), h = lane >> 5;
#pragma unroll
        for (int kt = 0; kt < 4; ++kt)
#pragma unroll
            for (int i = 0; i < 8; ++i) {
                int k = kt * 16 + h * 8 + i;
                float x = zt[k * 128 + pl];
                unsigned short hb = rne_bf16(x);
                float hf = __uint_as_float((unsigned)hb << 16);
                ah[kt][i] = (short)hb;
                al[kt][i] = (short)rne_bf16(x - hf);
            }
    }

    const int plbase = wv * 32 + 4 * (lane >> 5);

    float mreg[16];
#pragma unroll
    for (int r = 0; r < 16; ++r) mreg[r] = 3.4e38f;

    bf16x8 hA[4], lA[4], hB[4], lB[4];
    float  eA, eB;

    // ---- sweep 1: min_j s~  (per-wave, barrier-free, reg-dbuf prefetch)
    LOADB(hA, lA, eA, 0);
#pragma unroll 1
    for (int nt = 0; nt < 32; nt += 2) {
        LOADB(hB, lB, eB, nt + 1);
        {
            f32x16 acc;
#pragma unroll
            for (int r = 0; r < 16; ++r) acc[r] = 0.f;
            MFMA3(hA, lA, acc);
#pragma unroll
            for (int r = 0; r < 16; ++r) {
                float s = fmaf(-2.f, acc[r], eA);
                mreg[r] = fminf(mreg[r], s);
            }
        }
        if (nt + 2 < 32) LOADB(hA, lA, eA, nt + 2);
        {
            f32x16 acc;
#pragma unroll
            for (int r = 0; r < 16; ++r) acc[r] = 0.f;
            MFMA3(hB, lB, acc);
#pragma unroll
            for (int r = 0; r < 16; ++r) {
                float s = fmaf(-2.f, acc[r], eB);
                mreg[r] = fminf(mreg[r], s);
            }
        }
    }
    // butterfly min across the 32 cols (lanes sharing l>>5 hold same rows)
#pragma unroll
    for (int r = 0; r < 16; ++r)
        for (int d2 = 1; d2 <= 16; d2 <<= 1)
            mreg[r] = fminf(mreg[r], __shfl_xor(mreg[r], d2));

    // ---- sweep 2: recompute (bit-identical) and enqueue window hits
    LOADB(hA, lA, eA, 0);
#pragma unroll 1
    for (int nt = 0; nt < 32; nt += 2) {
        LOADB(hB, lB, eB, nt + 1);
        {
            f32x16 acc;
#pragma unroll
            for (int r = 0; r < 16; ++r) acc[r] = 0.f;
            MFMA3(hA, lA, acc);
            unsigned jj = (unsigned)(nt * 32 + (lane & 31));
#pragma unroll
            for (int r = 0; r < 16; ++r) {
                float s = fmaf(-2.f, acc[r], eA);
                if (s <= mreg[r] + WIN) {
                    unsigned slot = atomicAdd(&qcnt, 1u);
                    if (slot < QCAP)
                        queue[slot] = ((unsigned)(plbase + ((r & 3) + 8 * (r >> 2))) << 16) | jj;
                }
            }
        }
        if (nt + 2 < 32) LOADB(hA, lA, eA, nt + 2);
        {
            f32x16 acc;
#pragma unroll
            for (int r = 0; r < 16; ++r) acc[r] = 0.f;
            MFMA3(hB, lB, acc);
            unsigned jj = (unsigned)((nt + 1) * 32 + (lane & 31));
#pragma unroll
            for (int r = 0; r < 16; ++r) {
                float s = fmaf(-2.f, acc[r], eB);
                if (s <= mreg[r] + WIN) {
                    unsigned slot = atomicAdd(&qcnt, 1u);
                    if (slot < QCAP)
                        queue[slot] = ((unsigned)(plbase + ((r & 3) + 8 * (r >> 2))) << 16) | jj;
                }
            }
        }
    }
    __syncthreads();

    // ---- exact refine of candidates (bit-identical to r1-r5 formula)
    {
        int nq = (int)min(qcnt, (unsigned)QCAP);
        for (int e = tid; e < nq; e += 256) {
            unsigned u = queue[e];
            int pl = u >> 16, j = u & 0xFFFF;
            const float4* cr = (const float4*)(cb + ((size_t)j << 6));
            float a = 0.f;
#pragma unroll
            for (int q = 0; q < 16; ++q) {
                float4 c4 = cr[q];
                a = fmaf(zt[(4 * q + 0) * 128 + pl], c4.x, a);
                a = fmaf(zt[(4 * q + 1) * 128 + pl], c4.y, a);
                a = fmaf(zt[(4 * q + 2) * 128 + pl], c4.z, a);
                a = fmaf(zt[(4 * q + 3) * 128 + pl], c4.w, a);
            }
            float t1 = zzs[pl] + ee[j];
            float d  = fmaf(-2.f, a, t1);
            unsigned long long key =
                ((unsigned long long)__float_as_uint(d) << 32) | (unsigned long long)j;
            atomicMin(&best[pl], key);            // lexicographic (d, j): lowest idx on tie
        }
    }
    __syncthreads();
    if (tid < 128) {
        int bi = (int)(best[tid] & 0xFFFFFFFFull);
        ibuf[tid] = bi;
        idx_f[(size_t)g * 128 + tid] = (float)bi;
        atomicAdd(&counts[bi], 1);
    }
    __syncthreads();

    // ---- fused tail: z_q_st = fl(z + fl(q - z)), float4 stores; loss partial
    {
        int w4 = tid & 31, c8 = (tid >> 5) * 8;
        float4* zq4 = (float4*)(zq + zoff);
        size_t b0 = (size_t)ibuf[w4 * 4 + 0] << 6;
        size_t b1 = (size_t)ibuf[w4 * 4 + 1] << 6;
        size_t b2 = (size_t)ibuf[w4 * 4 + 2] << 6;
        size_t b3 = (size_t)ibuf[w4 * 4 + 3] << 6;
        double ls = 0.0;
#pragma unroll
        for (int i = 0; i < 8; ++i) {
            int c = c8 + i;
            float4 zv = zt4[c * 32 + w4];
            float q0 = cb[b0 + c], q1 = cb[b1 + c], q2 = cb[b2 + c], q3 = cb[b3 + c];
            float t0 = q0 - zv.x, t1 = q1 - zv.y, t2 = q2 - zv.z, t3 = q3 - zv.w;
            zq4[(size_t)c * 1024 + w4] =
                make_float4(zv.x + t0, zv.y + t1, zv.z + t2, zv.w + t3);
            ls += (double)t0 * t0 + (double)t1 * t1 + (double)t2 * t2 + (double)t3 * t3;
        }
#pragma unroll
        for (int off = 32; off > 0; off >>= 1) ls += __shfl_down(ls, off);
        if ((tid & 63) == 0) wsum[tid >> 6] = ls;
    }
    __syncthreads();
    if (tid == 0) partials[g] = wsum[0] + wsum[1] + wsum[2] + wsum[3];
}

// ---------------------------------------------------------------- scalars
__global__ __launch_bounds__(256) void vq_final(
    const int* __restrict__ counts, const double* __restrict__ partials,
    float* __restrict__ scalars)
{
    __shared__ double sh[256];
    __shared__ double sl[256];
    int t = threadIdx.x;
    double s = 0.0;
    for (int j = t; j < NUM_E; j += 256) {
        float em   = (float)counts[j] * (1.0f / 131072.0f);
        float term = em * logf(em + 1e-10f);
        s += (double)term;
    }
    double l = 0.0;
#pragma unroll
    for (int j = 0; j < AGRID / 256; ++j) l += partials[j * 256 + t];
    sh[t] = s;
    sl[t] = l;
    __syncthreads();
    for (int off = 128; off > 0; off >>= 1) {
        if (t < off) { sh[t] += sh[t + off]; sl[t] += sl[t + off]; }
        __syncthreads();
    }
    if (t == 0) {
        float m = (float)(sl[0] / 8388608.0);
        scalars[0] = m + 0.5f * m;           // mean1 + BETA*mean2
        scalars[1] = expf(-(float)sh[0]);    // perplexity
    }
}

// ---------------------------------------------------------------- launch
extern "C" void kernel_launch(void* const* d_in, const int* in_sizes, int n_in,
                              void* d_out, int out_size, void* d_ws, size_t ws_size,
                              hipStream_t stream)
{
    const float* z  = (const float*)d_in[0];
    const float* cb = (const float*)d_in[1];
    float* out     = (float*)d_out;
    float* zq      = out;                    // [32,64,64,64]
    float* scalars = out + ZQ_ELEM;          // loss, perplexity
    float* idx_f   = out + ZQ_ELEM + 2;      // [32,64,64] as float

    int*            counts   = (int*)d_ws;                               // 4 KB
    double*         partials = (double*)((char*)d_ws + 4096);            // 8 KB
    float*          ee       = (float*)((char*)d_ws + 12288);            // 4 KB
    unsigned short* ehi      = (unsigned short*)((char*)d_ws + 16384);   // 128 KB
    unsigned short* elo      = (unsigned short*)((char*)d_ws + 147456);  // 128 KB

    hipMemsetAsync(d_ws, 0, 4096, stream);                    // zero counts
    vq_prep  <<<4,     256, 0, stream>>>(cb, ee, ehi, elo);
    vq_argmin<<<AGRID, 256, 0, stream>>>(z, cb, ehi, elo, ee, idx_f, counts, zq, partials);
    vq_final <<<1,     256, 0, stream>>>(counts, partials, scalars);
}

// Round 7
// 113.528 us; speedup vs baseline: 2.4366x; 1.2440x over previous
//
#include <hip/hip_runtime.h>
#include <math.h>

#define NUM_E   1024
#define ZQ_ELEM 8388608         // 32*64*64*64
#define AGRID   512
#define QCAP    2048

typedef short bf16x8 __attribute__((ext_vector_type(8)));
typedef float f32x16 __attribute__((ext_vector_type(16)));

__device__ inline unsigned short rne_bf16(float v) {
    unsigned u = __float_as_uint(v);
    return (unsigned short)((u + 0x7FFFu + ((u >> 16) & 1u)) >> 16);  // RNE, finite-safe
}

// ---------------------------------------------------------------- prep: ee + bf16-hi B fragments
// B-frag layout for mfma_f32_32x32x16_bf16: lane l holds col j = nt*32+(l&31),
// k = kt*16 + (l>>5)*8 + i.  Packet index = (nt*4+kt)*64 + (l>>5)*32 + (j&31).
__global__ __launch_bounds__(256) void vq_prep(const float* __restrict__ cb,
                                               float* __restrict__ ee,
                                               unsigned short* __restrict__ ehi)
{
    int j = blockIdx.x * 256 + threadIdx.x;   // grid 4 -> 1024 codes
    const float* r = cb + (size_t)j * 64;
    float v[64];
#pragma unroll
    for (int k = 0; k < 64; ++k) v[k] = r[k];
    float a = 0.f;
#pragma unroll
    for (int k = 0; k < 64; ++k) a = fmaf(v[k], v[k], a);   // same chain as r1-r6
    ee[j] = a;

    int nt = j >> 5, jc = j & 31;
#pragma unroll
    for (int kt = 0; kt < 4; ++kt)
#pragma unroll
        for (int h = 0; h < 2; ++h) {
            bf16x8 vh;
#pragma unroll
            for (int i = 0; i < 8; ++i)
                vh[i] = (short)rne_bf16(v[kt * 16 + h * 8 + i]);
            *(bf16x8*)(ehi + ((size_t)(nt * 4 + kt) * 64 + h * 32 + jc) * 8) = vh;
        }
}

// exact refine of one (point, code): bit-identical to the r1-r6 passing formula
__device__ inline void refine_one(const float* zt, const float* zzs,
                                  const float* ee, const float* cb,
                                  unsigned long long* best, int pl, int j)
{
    const float4* cr = (const float4*)(cb + ((size_t)j << 6));
    float a = 0.f;
#pragma unroll
    for (int q = 0; q < 16; ++q) {
        float4 c4 = cr[q];
        a = fmaf(zt[(4 * q + 0) * 256 + pl], c4.x, a);
        a = fmaf(zt[(4 * q + 1) * 256 + pl], c4.y, a);
        a = fmaf(zt[(4 * q + 2) * 256 + pl], c4.z, a);
        a = fmaf(zt[(4 * q + 3) * 256 + pl], c4.w, a);
    }
    float t1 = zzs[pl] + ee[j];
    float d  = fmaf(-2.f, a, t1);
    unsigned long long key =
        ((unsigned long long)__float_as_uint(d) << 32) | (unsigned long long)j;
    atomicMin(best + pl, key);               // lexicographic (d, j): lowest idx on tie
}

#define LOADB(H, EV, ntv) do {                                      \
    int _b = (ntv) * 4 * 64 + lane;                                 \
    _Pragma("unroll")                                               \
    for (int _k = 0; _k < 4; ++_k) H[_k] = eh8[_b + _k * 64];       \
    EV = ee[(ntv) * 32 + (lane & 31)];                              \
} while (0)

// ---------------------------------------------------------------- argmin + quant (fused, MFMA hi-hi filter)
// Block = 256 points (4 h-rows), 256 threads = 4 waves; wave wv owns rows wv*64..wv*64+63
// as two 32-row MFMA groups sharing each loaded B packet.
__global__ __launch_bounds__(256, 2) void vq_argmin(
    const float* __restrict__ z, const float* __restrict__ cb,
    const unsigned short* __restrict__ ehi, const float* __restrict__ ee,
    float* __restrict__ idx_f, int* __restrict__ counts,
    float* __restrict__ zq, double* __restrict__ partials)
{
    __shared__ float zt[64 * 256];             // 64 KB [k][p]
    __shared__ float zzs[256];
    __shared__ float wp[256];                  // per-point window
    __shared__ unsigned long long best[256];
    __shared__ unsigned int queue[QCAP];       // 8 KB: (pl<<16)|j
    __shared__ unsigned int qcnt;
    __shared__ int ibuf[256];
    __shared__ double wsum[4];

    const int tid  = threadIdx.x;
    const int g    = blockIdx.x;               // 512 blocks: (b, h-quad)
    const int lane = tid & 63, wv = tid >> 6;
    const size_t zoff = ((size_t)(g >> 4) << 18) + (size_t)((g & 15) << 8);
    const float4* zb4 = (const float4*)(z + zoff);
    float4* zt4 = (float4*)zt;
    const bf16x8* eh8 = (const bf16x8*)ehi;

    // ---- stage zt[k][p] (coalesced: 1 KB per c-row), init best/qcnt
    {
        int w8 = tid & 63, c0 = tid >> 6;
#pragma unroll
        for (int i = 0; i < 16; ++i) {
            int c = c0 * 16 + i;
            zt4[c * 64 + w8] = zb4[(size_t)c * 1024 + w8];
        }
        best[tid] = 0xFFFFFFFFFFFFFFFFull;
        if (tid == 0) qcnt = 0;
    }
    __syncthreads();
    {                                           // zz: same 64-chain fmaf order as r1-r6
        float a = 0.f;
#pragma unroll
        for (int k = 0; k < 64; ++k) { float v = zt[k * 256 + tid]; a = fmaf(v, v, a); }
        zzs[tid] = a;
    }

    // ---- build A-fragments (z-hi) + per-point rigorous window
    bf16x8 ah0[4], ah1[4];
    {
        int h = lane >> 5;
#pragma unroll
        for (int g2 = 0; g2 < 2; ++g2) {
            int pl = wv * 64 + g2 * 32 + (lane & 31);
            float s1 = 0.f, sd = 0.f;
#pragma unroll
            for (int kt = 0; kt < 4; ++kt)
#pragma unroll
                for (int i = 0; i < 8; ++i) {
                    int k = kt * 16 + h * 8 + i;
                    float x = zt[k * 256 + pl];
                    unsigned short hb = rne_bf16(x);
                    float hf = __uint_as_float((unsigned)hb << 16);
                    if (g2 == 0) ah0[kt][i] = (short)hb; else ah1[kt][i] = (short)hb;
                    s1 += fabsf(x);
                    sd += fabsf(x - hf);
                }
            s1 += __shfl_xor(s1, 32);
            sd += __shfl_xor(sd, 32);
            // W = 2*eps_data + 4e-5 (d<->s offset roundings) + 1e-4 margin
            if (lane < 32) wp[pl] = 4.f * (s1 * 1.907e-6f + sd * 9.785e-4f) + 1.4e-4f;
        }
    }
    __syncthreads();                            // zzs/wp visible to all (fallback refine)

    float m0[16], m1[16];
#pragma unroll
    for (int r = 0; r < 16; ++r) { m0[r] = 3.4e38f; m1[r] = 3.4e38f; }

    bf16x8 hA[4], hB[4];
    float  eA, eB;

    // ---- sweep 1: per-row min of s~ (barrier-free, reg-dbuf)
    LOADB(hA, eA, 0);
#pragma unroll 1
    for (int nt = 0; nt < 32; nt += 2) {
        LOADB(hB, eB, nt + 1);
        {
            f32x16 a0, a1;
#pragma unroll
            for (int r = 0; r < 16; ++r) { a0[r] = 0.f; a1[r] = 0.f; }
            __builtin_amdgcn_s_setprio(1);
#pragma unroll
            for (int kt = 0; kt < 4; ++kt) {
                a0 = __builtin_amdgcn_mfma_f32_32x32x16_bf16(ah0[kt], hA[kt], a0, 0, 0, 0);
                a1 = __builtin_amdgcn_mfma_f32_32x32x16_bf16(ah1[kt], hA[kt], a1, 0, 0, 0);
            }
            __builtin_amdgcn_s_setprio(0);
#pragma unroll
            for (int r = 0; r < 16; ++r) {
                m0[r] = fminf(m0[r], fmaf(-2.f, a0[r], eA));
                m1[r] = fminf(m1[r], fmaf(-2.f, a1[r], eA));
            }
        }
        if (nt + 2 < 32) LOADB(hA, eA, nt + 2);
        {
            f32x16 a0, a1;
#pragma unroll
            for (int r = 0; r < 16; ++r) { a0[r] = 0.f; a1[r] = 0.f; }
            __builtin_amdgcn_s_setprio(1);
#pragma unroll
            for (int kt = 0; kt < 4; ++kt) {
                a0 = __builtin_amdgcn_mfma_f32_32x32x16_bf16(ah0[kt], hB[kt], a0, 0, 0, 0);
                a1 = __builtin_amdgcn_mfma_f32_32x32x16_bf16(ah1[kt], hB[kt], a1, 0, 0, 0);
            }
            __builtin_amdgcn_s_setprio(0);
#pragma unroll
            for (int r = 0; r < 16; ++r) {
                m0[r] = fminf(m0[r], fmaf(-2.f, a0[r], eB));
                m1[r] = fminf(m1[r], fmaf(-2.f, a1[r], eB));
            }
        }
    }
    // butterfly min across 32 col-lanes, then fold per-point window -> threshold
#pragma unroll
    for (int r = 0; r < 16; ++r) {
        for (int d2 = 1; d2 <= 16; d2 <<= 1) {
            m0[r] = fminf(m0[r], __shfl_xor(m0[r], d2));
            m1[r] = fminf(m1[r], __shfl_xor(m1[r], d2));
        }
        int row0 = wv * 64 + 4 * (lane >> 5) + (r & 3) + 8 * (r >> 2);
        m0[r] += wp[row0];
        m1[r] += wp[row0 + 32];
    }

    // ---- sweep 2: recompute, enqueue window hits (overflow -> inline exact refine)
    LOADB(hA, eA, 0);
#pragma unroll 1
    for (int nt = 0; nt < 32; nt += 2) {
        LOADB(hB, eB, nt + 1);
        {
            f32x16 a0, a1;
#pragma unroll
            for (int r = 0; r < 16; ++r) { a0[r] = 0.f; a1[r] = 0.f; }
            __builtin_amdgcn_s_setprio(1);
#pragma unroll
            for (int kt = 0; kt < 4; ++kt) {
                a0 = __builtin_amdgcn_mfma_f32_32x32x16_bf16(ah0[kt], hA[kt], a0, 0, 0, 0);
                a1 = __builtin_amdgcn_mfma_f32_32x32x16_bf16(ah1[kt], hA[kt], a1, 0, 0, 0);
            }
            __builtin_amdgcn_s_setprio(0);
            unsigned jj = (unsigned)(nt * 32 + (lane & 31));
#pragma unroll
            for (int r = 0; r < 16; ++r) {
                int pl = wv * 64 + 4 * (lane >> 5) + (r & 3) + 8 * (r >> 2);
                if (fmaf(-2.f, a0[r], eA) <= m0[r]) {
                    unsigned slot = atomicAdd(&qcnt, 1u);
                    if (slot < QCAP) queue[slot] = ((unsigned)pl << 16) | jj;
                    else refine_one(zt, zzs, ee, cb, best, pl, (int)jj);
                }
                if (fmaf(-2.f, a1[r], eA) <= m1[r]) {
                    unsigned slot = atomicAdd(&qcnt, 1u);
                    if (slot < QCAP) queue[slot] = ((unsigned)(pl + 32) << 16) | jj;
                    else refine_one(zt, zzs, ee, cb, best, pl + 32, (int)jj);
                }
            }
        }
        if (nt + 2 < 32) LOADB(hA, eA, nt + 2);
        {
            f32x16 a0, a1;
#pragma unroll
            for (int r = 0; r < 16; ++r) { a0[r] = 0.f; a1[r] = 0.f; }
            __builtin_amdgcn_s_setprio(1);
#pragma unroll
            for (int kt = 0; kt < 4; ++kt) {
                a0 = __builtin_amdgcn_mfma_f32_32x32x16_bf16(ah0[kt], hB[kt], a0, 0, 0, 0);
                a1 = __builtin_amdgcn_mfma_f32_32x32x16_bf16(ah1[kt], hB[kt], a1, 0, 0, 0);
            }
            __builtin_amdgcn_s_setprio(0);
            unsigned jj = (unsigned)((nt + 1) * 32 + (lane & 31));
#pragma unroll
            for (int r = 0; r < 16; ++r) {
                int pl = wv * 64 + 4 * (lane >> 5) + (r & 3) + 8 * (r >> 2);
                if (fmaf(-2.f, a0[r], eB) <= m0[r]) {
                    unsigned slot = atomicAdd(&qcnt, 1u);
                    if (slot < QCAP) queue[slot] = ((unsigned)pl << 16) | jj;
                    else refine_one(zt, zzs, ee, cb, best, pl, (int)jj);
                }
                if (fmaf(-2.f, a1[r], eB) <= m1[r]) {
                    unsigned slot = atomicAdd(&qcnt, 1u);
                    if (slot < QCAP) queue[slot] = ((unsigned)(pl + 32) << 16) | jj;
                    else refine_one(zt, zzs, ee, cb, best, pl + 32, (int)jj);
                }
            }
        }
    }
    __syncthreads();

    // ---- exact refine of queued candidates
    {
        int nq = (int)min(qcnt, (unsigned)QCAP);
        for (int e = tid; e < nq; e += 256) {
            unsigned u = queue[e];
            refine_one(zt, zzs, ee, cb, best, (int)(u >> 16), (int)(u & 0xFFFFu));
        }
    }
    __syncthreads();
    {
        int bi = (int)(best[tid] & 0xFFFFFFFFull);
        ibuf[tid] = bi;
        idx_f[(size_t)g * 256 + tid] = (float)bi;
        atomicAdd(&counts[bi], 1);
    }
    __syncthreads();

    // ---- fused tail: z_q_st = fl(z + fl(q - z)), float4 stores; loss partial
    {
        int w4 = tid & 63, cq = tid >> 6;
        float4* zq4 = (float4*)(zq + zoff);
        size_t b0 = (size_t)ibuf[w4 * 4 + 0] << 6;
        size_t b1 = (size_t)ibuf[w4 * 4 + 1] << 6;
        size_t b2 = (size_t)ibuf[w4 * 4 + 2] << 6;
        size_t b3 = (size_t)ibuf[w4 * 4 + 3] << 6;
        double ls = 0.0;
#pragma unroll
        for (int i = 0; i < 16; ++i) {
            int c = cq * 16 + i;
            float4 zv = zt4[c * 64 + w4];
            float q0 = cb[b0 + c], q1 = cb[b1 + c], q2 = cb[b2 + c], q3 = cb[b3 + c];
            float t0 = q0 - zv.x, t1 = q1 - zv.y, t2 = q2 - zv.z, t3 = q3 - zv.w;
            zq4[(size_t)c * 1024 + w4] =
                make_float4(zv.x + t0, zv.y + t1, zv.z + t2, zv.w + t3);
            ls += (double)t0 * t0 + (double)t1 * t1 + (double)t2 * t2 + (double)t3 * t3;
        }
#pragma unroll
        for (int off = 32; off > 0; off >>= 1) ls += __shfl_down(ls, off);
        if ((tid & 63) == 0) wsum[tid >> 6] = ls;
    }
    __syncthreads();
    if (tid == 0) partials[g] = wsum[0] + wsum[1] + wsum[2] + wsum[3];
}

// ---------------------------------------------------------------- scalars
__global__ __launch_bounds__(256) void vq_final(
    const int* __restrict__ counts, const double* __restrict__ partials,
    float* __restrict__ scalars)
{
    __shared__ double sh[256];
    __shared__ double sl[256];
    int t = threadIdx.x;
    double s = 0.0;
    for (int j = t; j < NUM_E; j += 256) {
        float em   = (float)counts[j] * (1.0f / 131072.0f);
        float term = em * logf(em + 1e-10f);
        s += (double)term;
    }
    double l = 0.0;
#pragma unroll
    for (int j = 0; j < AGRID / 256; ++j) l += partials[j * 256 + t];
    sh[t] = s;
    sl[t] = l;
    __syncthreads();
    for (int off = 128; off > 0; off >>= 1) {
        if (t < off) { sh[t] += sh[t + off]; sl[t] += sl[t + off]; }
        __syncthreads();
    }
    if (t == 0) {
        float m = (float)(sl[0] / 8388608.0);
        scalars[0] = m + 0.5f * m;           // mean1 + BETA*mean2
        scalars[1] = expf(-(float)sh[0]);    // perplexity
    }
}

// ---------------------------------------------------------------- launch
extern "C" void kernel_launch(void* const* d_in, const int* in_sizes, int n_in,
                              void* d_out, int out_size, void* d_ws, size_t ws_size,
                              hipStream_t stream)
{
    const float* z  = (const float*)d_in[0];
    const float* cb = (const float*)d_in[1];
    float* out     = (float*)d_out;
    float* zq      = out;                    // [32,64,64,64]
    float* scalars = out + ZQ_ELEM;          // loss, perplexity
    float* idx_f   = out + ZQ_ELEM + 2;      // [32,64,64] as float

    int*            counts   = (int*)d_ws;                             // 4 KB
    double*         partials = (double*)((char*)d_ws + 4096);          // 4 KB
    float*          ee       = (float*)((char*)d_ws + 8192);           // 4 KB
    unsigned short* ehi      = (unsigned short*)((char*)d_ws + 12288); // 128 KB

    hipMemsetAsync(d_ws, 0, 4096, stream);                    // zero counts
    vq_prep  <<<4,     256, 0, stream>>>(cb, ee, ehi);
    vq_argmin<<<AGRID, 256, 0, stream>>>(z, cb, ehi, ee, idx_f, counts, zq, partials);
    vq_final <<<1,     256, 0, stream>>>(counts, partials, scalars);
}

// Round 8
// 111.682 us; speedup vs baseline: 2.4769x; 1.0165x over previous
//
#include <hip/hip_runtime.h>
#include <math.h>

#define NUM_E   1024
#define ZQ_ELEM 8388608         // 32*64*64*64
#define AGRID   1024
#define QCAP    2048

typedef short bf16x8 __attribute__((ext_vector_type(8)));
typedef float f32x16 __attribute__((ext_vector_type(16)));

__device__ inline unsigned short rne_bf16(float v) {
    unsigned u = __float_as_uint(v);
    return (unsigned short)((u + 0x7FFFu + ((u >> 16) & 1u)) >> 16);  // RNE, finite-safe
}

// ---------------------------------------------------------------- prep: ee + bf16-hi B fragments
// B-frag layout for mfma_f32_32x32x16_bf16: lane l holds col j = nt*32+(l&31),
// k = kt*16 + (l>>5)*8 + i.  Packet index = (nt*4+kt)*64 + (l>>5)*32 + (j&31).
__global__ __launch_bounds__(256) void vq_prep(const float* __restrict__ cb,
                                               float* __restrict__ ee,
                                               unsigned short* __restrict__ ehi)
{
    int j = blockIdx.x * 256 + threadIdx.x;   // grid 4 -> 1024 codes
    const float* r = cb + (size_t)j * 64;
    float v[64];
#pragma unroll
    for (int k = 0; k < 64; ++k) v[k] = r[k];
    float a = 0.f;
#pragma unroll
    for (int k = 0; k < 64; ++k) a = fmaf(v[k], v[k], a);   // same chain as r1-r7
    ee[j] = a;

    int nt = j >> 5, jc = j & 31;
#pragma unroll
    for (int kt = 0; kt < 4; ++kt)
#pragma unroll
        for (int h = 0; h < 2; ++h) {
            bf16x8 vh;
#pragma unroll
            for (int i = 0; i < 8; ++i)
                vh[i] = (short)rne_bf16(v[kt * 16 + h * 8 + i]);
            *(bf16x8*)(ehi + ((size_t)(nt * 4 + kt) * 64 + h * 32 + jc) * 8) = vh;
        }
}

// exact refine of one (point, code): bit-identical to the r1-r7 passing formula.
// z read from global (zb = z + block offset), stride 4096 floats per k.
__device__ inline void refine_one(const float* zb, const float* zzs,
                                  const float* ee, const float* cb,
                                  unsigned long long* best, int pl, int j)
{
    const float4* cr = (const float4*)(cb + ((size_t)j << 6));
    float a = 0.f;
#pragma unroll
    for (int q = 0; q < 16; ++q) {
        float4 c4 = cr[q];
        a = fmaf(zb[(size_t)(4 * q + 0) * 4096 + pl], c4.x, a);
        a = fmaf(zb[(size_t)(4 * q + 1) * 4096 + pl], c4.y, a);
        a = fmaf(zb[(size_t)(4 * q + 2) * 4096 + pl], c4.z, a);
        a = fmaf(zb[(size_t)(4 * q + 3) * 4096 + pl], c4.w, a);
    }
    float t1 = zzs[pl] + ee[j];
    float d  = fmaf(-2.f, a, t1);
    unsigned long long key =
        ((unsigned long long)__float_as_uint(d) << 32) | (unsigned long long)j;
    atomicMin(best + pl, key);               // lexicographic (d, j): lowest idx on tie
}

#define LOADB(H, EV, ntv) do {                                      \
    int _b = (ntv) * 4 * 64 + lane;                                 \
    _Pragma("unroll")                                               \
    for (int _k = 0; _k < 4; ++_k) H[_k] = eh8[_b + _k * 64];       \
    EV = ee[(ntv) * 32 + (lane & 31)];                              \
} while (0)

// ---------------------------------------------------------------- argmin + quant (fused)
// Block = 128 points (2 h-rows), 256 threads = 4 waves; wave wv owns rows wv*32..wv*32+31.
// 1024 blocks -> 4 blocks/CU -> 4 waves/SIMD (the round-7 fix: TLP for latency hiding).
__global__ __launch_bounds__(256, 4) void vq_argmin(
    const float* __restrict__ z, const float* __restrict__ cb,
    const unsigned short* __restrict__ ehi, const float* __restrict__ ee,
    float* __restrict__ idx_f, int* __restrict__ counts,
    float* __restrict__ zq, double* __restrict__ partials)
{
    __shared__ float zzs[128];
    __shared__ float wp[128];                  // per-point rigorous window
    __shared__ unsigned long long best[128];
    __shared__ unsigned int queue[QCAP];       // 8 KB: (pl<<16)|j
    __shared__ unsigned int qcnt;
    __shared__ unsigned int oflow;
    __shared__ int ibuf[128];
    __shared__ double wsum[4];

    const int tid  = threadIdx.x;
    const int g    = blockIdx.x;               // 1024 blocks: (b, h-pair)
    const int lane = tid & 63, wv = tid >> 6;
    const size_t zoff = ((size_t)(g >> 5) << 18) + (size_t)((g & 31) << 7);
    const float* zb = z + zoff;
    const bf16x8* eh8 = (const bf16x8*)ehi;

    if (tid < 128) best[tid] = 0xFFFFFFFFFFFFFFFFull;
    if (tid == 0) { qcnt = 0; oflow = 0; }

    // ---- zz: exact 64-chain fmaf order (same as r1-r7), coalesced global reads
    if (tid < 128) {
        float vv[64];
#pragma unroll
        for (int k = 0; k < 64; ++k) vv[k] = zb[(size_t)k * 4096 + tid];
        float a = 0.f;
#pragma unroll
        for (int k = 0; k < 64; ++k) a = fmaf(vv[k], vv[k], a);
        zzs[tid] = a;
    }

    // ---- A-fragment (z-hi) + per-point window; one 32-row group per wave
    bf16x8 ah[4];
    {
        int h = lane >> 5;
        int pl = wv * 32 + (lane & 31);
        float s1 = 0.f, sd = 0.f;
#pragma unroll
        for (int kt = 0; kt < 4; ++kt)
#pragma unroll
            for (int i = 0; i < 8; ++i) {
                int k = kt * 16 + h * 8 + i;
                float x = zb[(size_t)k * 4096 + pl];
                unsigned short hb = rne_bf16(x);
                float hf = __uint_as_float((unsigned)hb << 16);
                ah[kt][i] = (short)hb;
                s1 += fabsf(x);
                sd += fabsf(x - hf);
            }
        s1 += __shfl_xor(s1, 32);
        sd += __shfl_xor(sd, 32);
        // W = 2*eps_data bound (x2 margin) + 4e-5 (d<->s offset roundings) + 1e-4 margin
        if (lane < 32) wp[pl] = 4.f * (s1 * 1.907e-6f + sd * 9.785e-4f) + 1.4e-4f;
    }
    __syncthreads();                           // zzs/wp visible block-wide

    float m[16];
#pragma unroll
    for (int r = 0; r < 16; ++r) m[r] = 3.4e38f;

    bf16x8 hA[4], hB[4];
    float  eA, eB;

    // ---- sweep 1: per-row min of s~ (barrier-free, ping-pong prefetch)
    LOADB(hA, eA, 0);
#pragma unroll 1
    for (int nt = 0; nt < 32; nt += 2) {
        LOADB(hB, eB, nt + 1);
        {
            f32x16 acc;
#pragma unroll
            for (int r = 0; r < 16; ++r) acc[r] = 0.f;
#pragma unroll
            for (int kt = 0; kt < 4; ++kt)
                acc = __builtin_amdgcn_mfma_f32_32x32x16_bf16(ah[kt], hA[kt], acc, 0, 0, 0);
#pragma unroll
            for (int r = 0; r < 16; ++r) m[r] = fminf(m[r], fmaf(-2.f, acc[r], eA));
        }
        if (nt + 2 < 32) LOADB(hA, eA, nt + 2);
        {
            f32x16 acc;
#pragma unroll
            for (int r = 0; r < 16; ++r) acc[r] = 0.f;
#pragma unroll
            for (int kt = 0; kt < 4; ++kt)
                acc = __builtin_amdgcn_mfma_f32_32x32x16_bf16(ah[kt], hB[kt], acc, 0, 0, 0);
#pragma unroll
            for (int r = 0; r < 16; ++r) m[r] = fminf(m[r], fmaf(-2.f, acc[r], eB));
        }
    }
    // butterfly min across 32 col-lanes, then fold per-point window -> threshold
#pragma unroll
    for (int r = 0; r < 16; ++r) {
        for (int d2 = 1; d2 <= 16; d2 <<= 1)
            m[r] = fminf(m[r], __shfl_xor(m[r], d2));
        m[r] += wp[wv * 32 + 4 * (lane >> 5) + (r & 3) + 8 * (r >> 2)];
    }

    // ---- sweep 2: recompute (bit-identical), __any-guarded enqueue; overflow -> flag
    LOADB(hA, eA, 0);
#pragma unroll 1
    for (int nt = 0; nt < 32; nt += 2) {
        LOADB(hB, eB, nt + 1);
        {
            f32x16 acc;
#pragma unroll
            for (int r = 0; r < 16; ++r) acc[r] = 0.f;
#pragma unroll
            for (int kt = 0; kt < 4; ++kt)
                acc = __builtin_amdgcn_mfma_f32_32x32x16_bf16(ah[kt], hA[kt], acc, 0, 0, 0);
            unsigned jj = (unsigned)(nt * 32 + (lane & 31));
#pragma unroll
            for (int r = 0; r < 16; ++r) {
                bool hit = fmaf(-2.f, acc[r], eA) <= m[r];
                if (__any(hit)) {
                    if (hit) {
                        int pl = wv * 32 + 4 * (lane >> 5) + (r & 3) + 8 * (r >> 2);
                        unsigned slot = atomicAdd(&qcnt, 1u);
                        if (slot < QCAP) queue[slot] = ((unsigned)pl << 16) | jj;
                        else oflow = 1;
                    }
                }
            }
        }
        if (nt + 2 < 32) LOADB(hA, eA, nt + 2);
        {
            f32x16 acc;
#pragma unroll
            for (int r = 0; r < 16; ++r) acc[r] = 0.f;
#pragma unroll
            for (int kt = 0; kt < 4; ++kt)
                acc = __builtin_amdgcn_mfma_f32_32x32x16_bf16(ah[kt], hB[kt], acc, 0, 0, 0);
            unsigned jj = (unsigned)((nt + 1) * 32 + (lane & 31));
#pragma unroll
            for (int r = 0; r < 16; ++r) {
                bool hit = fmaf(-2.f, acc[r], eB) <= m[r];
                if (__any(hit)) {
                    if (hit) {
                        int pl = wv * 32 + 4 * (lane >> 5) + (r & 3) + 8 * (r >> 2);
                        unsigned slot = atomicAdd(&qcnt, 1u);
                        if (slot < QCAP) queue[slot] = ((unsigned)pl << 16) | jj;
                        else oflow = 1;
                    }
                }
            }
        }
    }
    __syncthreads();

    // ---- exact refine (expected ~175 candidates; oflow path is a never-taken safety net)
    if (oflow) {
        if (tid < 128)
            for (int j = 0; j < NUM_E; ++j) refine_one(zb, zzs, ee, cb, best, tid, j);
    } else {
        int nq = (int)qcnt;
        for (int e = tid; e < nq; e += 256) {
            unsigned u = queue[e];
            refine_one(zb, zzs, ee, cb, best, (int)(u >> 16), (int)(u & 0xFFFFu));
        }
    }
    __syncthreads();
    if (tid < 128) {
        int bi = (int)(best[tid] & 0xFFFFFFFFull);
        ibuf[tid] = bi;
        idx_f[(size_t)g * 128 + tid] = (float)bi;
        atomicAdd(&counts[bi], 1);
    }
    __syncthreads();

    // ---- fused tail: z_q_st = fl(z + fl(q - z)), float4 stores; loss partial
    {
        int w4 = tid & 31, c8 = (tid >> 5) * 8;
        const float4* zb4 = (const float4*)zb;
        float4* zq4 = (float4*)(zq + zoff);
        size_t b0 = (size_t)ibuf[w4 * 4 + 0] << 6;
        size_t b1 = (size_t)ibuf[w4 * 4 + 1] << 6;
        size_t b2 = (size_t)ibuf[w4 * 4 + 2] << 6;
        size_t b3 = (size_t)ibuf[w4 * 4 + 3] << 6;
        double ls = 0.0;
#pragma unroll
        for (int i = 0; i < 8; ++i) {
            int c = c8 + i;
            float4 zv = zb4[(size_t)c * 1024 + w4];
            float q0 = cb[b0 + c], q1 = cb[b1 + c], q2 = cb[b2 + c], q3 = cb[b3 + c];
            float t0 = q0 - zv.x, t1 = q1 - zv.y, t2 = q2 - zv.z, t3 = q3 - zv.w;
            zq4[(size_t)c * 1024 + w4] =
                make_float4(zv.x + t0, zv.y + t1, zv.z + t2, zv.w + t3);
            ls += (double)t0 * t0 + (double)t1 * t1 + (double)t2 * t2 + (double)t3 * t3;
        }
#pragma unroll
        for (int off = 32; off > 0; off >>= 1) ls += __shfl_down(ls, off);
        if ((tid & 63) == 0) wsum[tid >> 6] = ls;
    }
    __syncthreads();
    if (tid == 0) partials[g] = wsum[0] + wsum[1] + wsum[2] + wsum[3];
}

// ---------------------------------------------------------------- scalars
__global__ __launch_bounds__(256) void vq_final(
    const int* __restrict__ counts, const double* __restrict__ partials,
    float* __restrict__ scalars)
{
    __shared__ double sh[256];
    __shared__ double sl[256];
    int t = threadIdx.x;
    double s = 0.0;
    for (int j = t; j < NUM_E; j += 256) {
        float em   = (float)counts[j] * (1.0f / 131072.0f);
        float term = em * logf(em + 1e-10f);
        s += (double)term;
    }
    double l = 0.0;
#pragma unroll
    for (int j = 0; j < AGRID / 256; ++j) l += partials[j * 256 + t];
    sh[t] = s;
    sl[t] = l;
    __syncthreads();
    for (int off = 128; off > 0; off >>= 1) {
        if (t < off) { sh[t] += sh[t + off]; sl[t] += sl[t + off]; }
        __syncthreads();
    }
    if (t == 0) {
        float mm = (float)(sl[0] / 8388608.0);
        scalars[0] = mm + 0.5f * mm;         // mean1 + BETA*mean2
        scalars[1] = expf(-(float)sh[0]);    // perplexity
    }
}

// ---------------------------------------------------------------- launch
extern "C" void kernel_launch(void* const* d_in, const int* in_sizes, int n_in,
                              void* d_out, int out_size, void* d_ws, size_t ws_size,
                              hipStream_t stream)
{
    const float* z  = (const float*)d_in[0];
    const float* cb = (const float*)d_in[1];
    float* out     = (float*)d_out;
    float* zq      = out;                    // [32,64,64,64]
    float* scalars = out + ZQ_ELEM;          // loss, perplexity
    float* idx_f   = out + ZQ_ELEM + 2;      // [32,64,64] as float

    int*            counts   = (int*)d_ws;                             // 4 KB
    double*         partials = (double*)((char*)d_ws + 4096);          // 8 KB
    float*          ee       = (float*)((char*)d_ws + 12288);          // 4 KB
    unsigned short* ehi      = (unsigned short*)((char*)d_ws + 16384); // 128 KB

    hipMemsetAsync(d_ws, 0, 4096, stream);                    // zero counts
    vq_prep  <<<4,     256, 0, stream>>>(cb, ee, ehi);
    vq_argmin<<<AGRID, 256, 0, stream>>>(z, cb, ehi, ee, idx_f, counts, zq, partials);
    vq_final <<<1,     256, 0, stream>>>(counts, partials, scalars);
}